// Round 1
// baseline (8166.441 us; speedup 1.0000x reference)
//
#include <hip/hip_runtime.h>

typedef __bf16 bf16_t;
typedef bf16_t bf16x8 __attribute__((ext_vector_type(8)));
typedef float  floatx4 __attribute__((ext_vector_type(4)));
typedef unsigned short u16;

#define DEV __device__ __forceinline__

static constexpr int B_  = 256;
static constexpr int T_  = 64;
static constexpr int H_  = 512;
static constexpr int G_  = 2048;   // 4*H
static constexpr int INS = 500;
static constexpr int NDP = 16640;  // padded OUT_DIM
static constexpr int NDR = 16532;  // real OUT_DIM

DEV u16 f2bf(float f) {
  unsigned u = __builtin_bit_cast(unsigned, f);
  u += 0x7FFFu + ((u >> 16) & 1u);
  return (u16)(u >> 16);
}
DEV float bf2f(u16 h) {
  unsigned u = ((unsigned)h) << 16;
  return __builtin_bit_cast(float, u);
}
DEV float sigm(float x)  { return 1.f / (1.f + __expf(-x)); }
DEV float tanh_(float x) { return 1.f - 2.f / (__expf(2.f * x) + 1.f); }

// ---------------------------------------------------------------- prep kernels
__global__ void prep_weights_kernel(
    const float* __restrict__ w_ih0, const float* __restrict__ w_hh0,
    const float* __restrict__ b_ih0, const float* __restrict__ b_hh0,
    const float* __restrict__ w_ih1, const float* __restrict__ w_hh1,
    const float* __restrict__ b_ih1, const float* __restrict__ b_hh1,
    const float* __restrict__ fc_w,  const float* __restrict__ fc_b,
    u16* __restrict__ wih0b, u16* __restrict__ whh0b,
    u16* __restrict__ w1b,   u16* __restrict__ fcwb,
    float* __restrict__ bias0p, float* __restrict__ bias1p,
    float* __restrict__ fcbp)
{
  const int gsz = gridDim.x * blockDim.x;
  const int g0  = blockIdx.x * blockDim.x + threadIdx.x;
  // permuted gate order: p = (j>>4)*64 + (j&15)*4 + g  (j = hidden, g = i/f/g/o)
  for (int i = g0; i < 2048 * 512; i += gsz) {
    int pp = i >> 9, k = i & 511;
    int s = pp >> 6, rr = pp & 63, jj = rr >> 2, g = rr & 3;
    int srow = g * 512 + s * 16 + jj;
    wih0b[i] = f2bf(k < INS ? w_ih0[(size_t)srow * INS + k] : 0.f);
    whh0b[i] = f2bf(w_hh0[(size_t)srow * 512 + k]);
  }
  for (int i = g0; i < 2048 * 1024; i += gsz) {
    int pp = i >> 10, k = i & 1023;
    int s = pp >> 6, rr = pp & 63, jj = rr >> 2, g = rr & 3;
    int srow = g * 512 + s * 16 + jj;
    float v = (k < 512) ? w_ih1[(size_t)srow * 512 + k]
                        : w_hh1[(size_t)srow * 512 + (k - 512)];
    w1b[i] = f2bf(v);
  }
  for (int i = g0; i < NDP * 512; i += gsz) {
    int n = i >> 9, k = i & 511;
    fcwb[i] = f2bf(n < NDR ? fc_w[(size_t)n * 512 + k] : 0.f);
  }
  for (int i = g0; i < 2048; i += gsz) {
    int s = i >> 6, rr = i & 63, jj = rr >> 2, g = rr & 3;
    int srow = g * 512 + s * 16 + jj;
    bias0p[i] = b_ih0[srow] + b_hh0[srow];
    bias1p[i] = b_ih1[srow] + b_hh1[srow];
  }
  for (int i = g0; i < NDP; i += gsz) fcbp[i] = (i < NDR) ? fc_b[i] : 0.f;
}

__global__ void prep_x_kernel(const float* __restrict__ x, u16* __restrict__ xb) {
  const int gsz = gridDim.x * blockDim.x;
  for (int i = blockIdx.x * blockDim.x + threadIdx.x; i < T_ * B_ * 512; i += gsz) {
    int k = i & 511;
    int b = (i >> 9) & 255;
    int t = i >> 17;
    float v = (k < INS) ? x[((size_t)b * T_ + t) * INS + k] : 0.f;
    xb[i] = f2bf(v);
  }
}

__global__ void prep_sigma_kernel(const float* __restrict__ raw,
                                  u16* __restrict__ Gb, u16* __restrict__ Ldb,
                                  float* __restrict__ idio)
{
  const int gsz = gridDim.x * blockDim.x;
  const int g0  = blockIdx.x * blockDim.x + threadIdx.x;
  for (int i = g0; i < 256 * 512 * 32; i += gsz) {
    int b = i >> 14, rr = i & 16383, n = rr >> 5, f = rr & 31;
    const float* rb = raw + (size_t)b * NDP;
    float ld = (n < 500) ? rb[n * 32 + f] : 0.f;
    float fv = __expf(rb[16000 + f]);
    Ldb[i] = f2bf(ld);
    Gb[i]  = f2bf(ld * fv);
  }
  for (int i = g0; i < 256 * 512; i += gsz) {
    int b = i >> 9, a = i & 511;
    if (a < 500) idio[(size_t)b * 500 + a] = __expf(raw[(size_t)b * NDP + 16032 + a]);
  }
}

// ---------------------------------------------------------------- GEMM: C[M][N] = A[M][K] @ Bw[N][K]^T + bias
template <int OUT_BF16>
__global__ __launch_bounds__(256) void gemm_bt(
    const u16* __restrict__ A, const u16* __restrict__ Bw,
    const float* __restrict__ bias, void* __restrict__ C,
    int M, int N, int K)
{
  __shared__ alignas(16) u16 As[128 * 32];
  __shared__ alignas(16) u16 Bs[128 * 32];
  const int tid = threadIdx.x;
  const int wave = tid >> 6, lane = tid & 63;
  const int m0 = blockIdx.y * 128, n0 = blockIdx.x * 128;
  const int wr = wave >> 1, wc = wave & 1;

  floatx4 zero = {0.f, 0.f, 0.f, 0.f};
  floatx4 acc[4][4];
#pragma unroll
  for (int i = 0; i < 4; i++)
#pragma unroll
    for (int j = 0; j < 4; j++) acc[i][j] = zero;

  uint4 ra[2], rb[2];
#pragma unroll
  for (int i = 0; i < 2; i++) {
    int idx = tid + (i << 8);
    int row = idx >> 2, ks = idx & 3;
    ra[i] = *(const uint4*)(A  + (size_t)(m0 + row) * K + ks * 8);
    rb[i] = *(const uint4*)(Bw + (size_t)(n0 + row) * K + ks * 8);
  }

  for (int kc = 0; kc < K; kc += 32) {
    __syncthreads();
#pragma unroll
    for (int i = 0; i < 2; i++) {
      int idx = tid + (i << 8);
      int row = idx >> 2, ks = idx & 3;
      int off = row * 32 + ((ks ^ (row & 3)) << 3);   // XOR swizzle vs bank conflicts
      *(uint4*)(As + off) = ra[i];
      *(uint4*)(Bs + off) = rb[i];
    }
    __syncthreads();
    if (kc + 32 < K) {
#pragma unroll
      for (int i = 0; i < 2; i++) {
        int idx = tid + (i << 8);
        int row = idx >> 2, ks = idx & 3;
        ra[i] = *(const uint4*)(A  + (size_t)(m0 + row) * K + kc + 32 + ks * 8);
        rb[i] = *(const uint4*)(Bw + (size_t)(n0 + row) * K + kc + 32 + ks * 8);
      }
    }
    const int kg = lane >> 4;
    bf16x8 af[4], bfr[4];
#pragma unroll
    for (int i = 0; i < 4; i++) {
      int rowa = wr * 64 + i * 16 + (lane & 15);
      af[i] = *(const bf16x8*)(As + rowa * 32 + ((kg ^ (rowa & 3)) << 3));
      int rowb = wc * 64 + i * 16 + (lane & 15);
      bfr[i] = *(const bf16x8*)(Bs + rowb * 32 + ((kg ^ (rowb & 3)) << 3));
    }
#pragma unroll
    for (int i = 0; i < 4; i++)
#pragma unroll
      for (int j = 0; j < 4; j++)
        acc[i][j] = __builtin_amdgcn_mfma_f32_16x16x32_bf16(af[i], bfr[j], acc[i][j], 0, 0, 0);
  }

  const int r0 = (lane >> 4) * 4, cl = lane & 15;
#pragma unroll
  for (int j = 0; j < 4; j++) {
    int col = n0 + wc * 64 + j * 16 + cl;
    float bv = bias[col];
#pragma unroll
    for (int i = 0; i < 4; i++) {
      int row = m0 + wr * 64 + i * 16 + r0;
#pragma unroll
      for (int r = 0; r < 4; r++) {
        float v = acc[i][j][r] + bv;
        if (OUT_BF16) ((u16*)C)[(size_t)(row + r) * N + col] = f2bf(v);
        else          ((float*)C)[(size_t)(row + r) * N + col] = v;
      }
    }
  }
}

// ---------------------------------------------------------------- LSTM layer 0
// 512 blocks: bm=blockIdx>>5 (16 batch groups of 16), bn=blockIdx&31 (32 hidden slices of 16).
// W_hh fragments live in registers; per-batch-group barrier (32 blocks) each step.
__global__ __launch_bounds__(256, 2) void lstm0_kernel(
    const u16* __restrict__ xg,     // [64][256][2048] bf16, permuted gate order
    const u16* __restrict__ whh,    // [2048][512] bf16, permuted rows
    u16* __restrict__ hping,        // [2][256][512]
    u16* __restrict__ h0all,        // [64][256][512]
    unsigned* __restrict__ bars)    // [16*32]
{
  const int tid = threadIdx.x;
  const int wave = tid >> 6, lane = tid & 63;
  const int bm = blockIdx.x >> 5;
  const int bn = blockIdx.x & 31;
  const int bbase = bm << 4;
  const int pbase = bn << 6;

  __shared__ alignas(16) u16 h_lds[16 * 512];
  __shared__ alignas(16) float gates_lds[16 * 64];

  bf16x8 wfrag[16];
  {
    const u16* wp = whh + (size_t)(pbase + wave * 16 + (lane & 15)) * 512 + (lane >> 4) * 8;
#pragma unroll
    for (int kc = 0; kc < 16; kc++) wfrag[kc] = *(const bf16x8*)(wp + kc * 32);
  }

  const int qb = tid >> 4, qj = tid & 15;
  float c = 0.f;
  unsigned target = 0;
  unsigned* mybar = bars + bm * 32;
  const floatx4 zero = {0.f, 0.f, 0.f, 0.f};

#pragma unroll 1
  for (int t = 0; t < 64; t++) {
    const int cur = t & 1, nxt = cur ^ 1;
    {
      const u16* hsrc = hping + cur * (B_ * H_) + bbase * H_;
#pragma unroll
      for (int i = 0; i < 4; i++) {
        int idx = tid + (i << 8);
        int b = idx >> 6, kg = idx & 63;
        *(uint4*)(h_lds + b * 512 + ((kg ^ (b & 7)) << 3)) = *(const uint4*)(hsrc + idx * 8);
      }
    }
    __syncthreads();
    floatx4 acc = zero;
    {
      const int b = lane & 15, qd = lane >> 4;
#pragma unroll
      for (int kc = 0; kc < 16; kc++) {
        int kgrp = kc * 4 + qd;
        bf16x8 a = *(const bf16x8*)(h_lds + b * 512 + ((kgrp ^ (b & 7)) << 3));
        acc = __builtin_amdgcn_mfma_f32_16x16x32_bf16(a, wfrag[kc], acc, 0, 0, 0);
      }
    }
    {
      int r0 = (lane >> 4) * 4, cc = wave * 16 + (lane & 15);
#pragma unroll
      for (int r = 0; r < 4; r++) gates_lds[(r0 + r) * 64 + cc] = acc[r];
    }
    __syncthreads();
    {
      const float4 gm = *(const float4*)(gates_lds + qb * 64 + qj * 4);
      const u16* xq = xg + ((size_t)t * B_ + bbase + qb) * G_ + pbase + qj * 4;
      ushort4 xr = *(const ushort4*)xq;
      float gi = gm.x + bf2f(xr.x);
      float gf = gm.y + bf2f(xr.y);
      float gg = gm.z + bf2f(xr.z);
      float go = gm.w + bf2f(xr.w);
      c = sigm(gf) * c + sigm(gi) * tanh_(gg);
      float h = sigm(go) * tanh_(c);
      u16 hb = f2bf(h);
      size_t hoff = (size_t)(bbase + qb) * H_ + (bn << 4) + qj;
      hping[nxt * (B_ * H_) + hoff] = hb;
      h0all[(size_t)t * (B_ * H_) + hoff] = hb;
    }
    target += 32;
    if (t < 63) {
      __threadfence();
      __syncthreads();
      if (tid == 0) {
        atomicAdd(mybar, 1u);
        while (__hip_atomic_load(mybar, __ATOMIC_RELAXED, __HIP_MEMORY_SCOPE_AGENT) < target)
          __builtin_amdgcn_s_sleep(1);
        __threadfence();
      }
      __syncthreads();
    }
  }
}

// ---------------------------------------------------------------- LSTM layer 1 (input proj folded in: K=1024 = [h0_t | h1])
__global__ __launch_bounds__(256, 2) void lstm1_kernel(
    const u16* __restrict__ h0all,  // [64][256][512]
    const u16* __restrict__ w1,     // [2048][1024] bf16 permuted rows, cols = [w_ih1 | w_hh1]
    const float* __restrict__ bias1p,
    u16* __restrict__ hping,        // [2][256][512]; final h1 ends in buffer 0
    unsigned* __restrict__ bars)
{
  const int tid = threadIdx.x;
  const int wave = tid >> 6, lane = tid & 63;
  const int bm = blockIdx.x >> 5;
  const int bn = blockIdx.x & 31;
  const int bbase = bm << 4;
  const int pbase = bn << 6;

  __shared__ alignas(16) u16 h_lds[2 * 16 * 512];
  __shared__ alignas(16) float gates_lds[16 * 64];

  bf16x8 wfrag[32];
  {
    const u16* wp = w1 + (size_t)(pbase + wave * 16 + (lane & 15)) * 1024 + (lane >> 4) * 8;
#pragma unroll
    for (int kc = 0; kc < 32; kc++) wfrag[kc] = *(const bf16x8*)(wp + kc * 32);
  }

  const int qb = tid >> 4, qj = tid & 15;
  const float4 bq = *(const float4*)(bias1p + pbase + qj * 4);
  float c = 0.f;
  unsigned target = 0;
  unsigned* mybar = bars + bm * 32;
  const floatx4 zero = {0.f, 0.f, 0.f, 0.f};

#pragma unroll 1
  for (int t = 0; t < 64; t++) {
    const int cur = t & 1, nxt = cur ^ 1;
    {
      const u16* s0 = h0all + (size_t)t * (B_ * H_) + bbase * H_;
      const u16* s1 = hping + cur * (B_ * H_) + bbase * H_;
#pragma unroll
      for (int i = 0; i < 4; i++) {
        int idx = tid + (i << 8);
        int b = idx >> 6, kg = idx & 63;
        int dst = b * 512 + ((kg ^ (b & 7)) << 3);
        *(uint4*)(h_lds + dst)        = *(const uint4*)(s0 + idx * 8);
        *(uint4*)(h_lds + 8192 + dst) = *(const uint4*)(s1 + idx * 8);
      }
    }
    __syncthreads();
    floatx4 acc = zero;
    {
      const int b = lane & 15, qd = lane >> 4;
#pragma unroll
      for (int kc = 0; kc < 32; kc++) {
        int reg = (kc >> 4) * 8192;
        int kgrp = (kc & 15) * 4 + qd;
        bf16x8 a = *(const bf16x8*)(h_lds + reg + b * 512 + ((kgrp ^ (b & 7)) << 3));
        acc = __builtin_amdgcn_mfma_f32_16x16x32_bf16(a, wfrag[kc], acc, 0, 0, 0);
      }
    }
    {
      int r0 = (lane >> 4) * 4, cc = wave * 16 + (lane & 15);
#pragma unroll
      for (int r = 0; r < 4; r++) gates_lds[(r0 + r) * 64 + cc] = acc[r];
    }
    __syncthreads();
    {
      const float4 gm = *(const float4*)(gates_lds + qb * 64 + qj * 4);
      float gi = gm.x + bq.x;
      float gf = gm.y + bq.y;
      float gg = gm.z + bq.z;
      float go = gm.w + bq.w;
      c = sigm(gf) * c + sigm(gi) * tanh_(gg);
      float h = sigm(go) * tanh_(c);
      size_t hoff = (size_t)(bbase + qb) * H_ + (bn << 4) + qj;
      hping[nxt * (B_ * H_) + hoff] = f2bf(h);
    }
    target += 32;
    if (t < 63) {
      __threadfence();
      __syncthreads();
      if (tid == 0) {
        atomicAdd(mybar, 1u);
        while (__hip_atomic_load(mybar, __ATOMIC_RELAXED, __HIP_MEMORY_SCOPE_AGENT) < target)
          __builtin_amdgcn_s_sleep(1);
        __threadfence();
      }
      __syncthreads();
    }
  }
}

// ---------------------------------------------------------------- Sigma: out[b] = G_b @ Ld_b^T + diag(idio)
__global__ __launch_bounds__(256) void sigma_kernel(
    const u16* __restrict__ Gb, const u16* __restrict__ Ldb,
    const float* __restrict__ idio, float* __restrict__ out)
{
  const int bz = blockIdx.z;
  const int n0 = blockIdx.y * 128;
  const int m0 = blockIdx.x * 128;
  __shared__ alignas(16) u16 As[128 * 32];
  __shared__ alignas(16) u16 Bs[128 * 32];
  const int tid = threadIdx.x, wave = tid >> 6, lane = tid & 63;
  const int wr = wave >> 1, wc = wave & 1;

  const u16* ga = Gb  + (size_t)bz * (512 * 32) + n0 * 32;
  const u16* gb = Ldb + (size_t)bz * (512 * 32) + m0 * 32;
#pragma unroll
  for (int i = 0; i < 2; i++) {
    int idx = tid + (i << 8);
    int row = idx >> 2, ks = idx & 3;
    int off = row * 32 + ((ks ^ (row & 3)) << 3);
    *(uint4*)(As + off) = *(const uint4*)(ga + idx * 8);
    *(uint4*)(Bs + off) = *(const uint4*)(gb + idx * 8);
  }
  __syncthreads();

  const int kg = lane >> 4;
  bf16x8 af[4], bfr[4];
#pragma unroll
  for (int i = 0; i < 4; i++) {
    int rowa = wr * 64 + i * 16 + (lane & 15);
    af[i] = *(const bf16x8*)(As + rowa * 32 + ((kg ^ (rowa & 3)) << 3));
    int rowb = wc * 64 + i * 16 + (lane & 15);
    bfr[i] = *(const bf16x8*)(Bs + rowb * 32 + ((kg ^ (rowb & 3)) << 3));
  }
  floatx4 zero = {0.f, 0.f, 0.f, 0.f};
  floatx4 acc[4][4];
#pragma unroll
  for (int i = 0; i < 4; i++)
#pragma unroll
    for (int j = 0; j < 4; j++)
      acc[i][j] = __builtin_amdgcn_mfma_f32_16x16x32_bf16(af[i], bfr[j], zero, 0, 0, 0);

  const int r0 = (lane >> 4) * 4, cl = lane & 15;
  float* ob = out + (size_t)bz * 250000;
#pragma unroll
  for (int j = 0; j < 4; j++) {
    int col = m0 + wc * 64 + j * 16 + cl;
#pragma unroll
    for (int i = 0; i < 4; i++) {
      int row = n0 + wr * 64 + i * 16 + r0;
#pragma unroll
      for (int r = 0; r < 4; r++) {
        int rr = row + r;
        if (rr < 500 && col < 500) {
          float v = acc[i][j][r];
          if (rr == col) v += idio[(size_t)bz * 500 + rr];
          ob[(size_t)rr * 500 + col] = v;
        }
      }
    }
  }
}

// ---------------------------------------------------------------- launcher
extern "C" void kernel_launch(void* const* d_in, const int* in_sizes, int n_in,
                              void* d_out, int out_size, void* d_ws, size_t ws_size,
                              hipStream_t stream)
{
  const float* x     = (const float*)d_in[0];
  const float* w_ih0 = (const float*)d_in[1];
  const float* w_hh0 = (const float*)d_in[2];
  const float* b_ih0 = (const float*)d_in[3];
  const float* b_hh0 = (const float*)d_in[4];
  const float* w_ih1 = (const float*)d_in[5];
  const float* w_hh1 = (const float*)d_in[6];
  const float* b_ih1 = (const float*)d_in[7];
  const float* b_hh1 = (const float*)d_in[8];
  const float* fc_w  = (const float*)d_in[9];
  const float* fc_b  = (const float*)d_in[10];
  float* out = (float*)d_out;

  char* p = (char*)d_ws;
  auto alloc = [&](size_t n) { char* r = p; p += (n + 255) & ~(size_t)255; return r; };

  u16*  xb     = (u16*)alloc((size_t)T_ * B_ * 512 * 2);
  u16*  wih0b  = (u16*)alloc((size_t)2048 * 512 * 2);
  u16*  whh0b  = (u16*)alloc((size_t)2048 * 512 * 2);
  u16*  w1b    = (u16*)alloc((size_t)2048 * 1024 * 2);
  u16*  fcwb   = (u16*)alloc((size_t)NDP * 512 * 2);
  float* bias0p = (float*)alloc(2048 * 4);
  float* bias1p = (float*)alloc(2048 * 4);
  float* fcbp   = (float*)alloc((size_t)NDP * 4);
  u16*  xg0    = (u16*)alloc((size_t)T_ * B_ * G_ * 2);
  u16*  h0all  = (u16*)alloc((size_t)T_ * B_ * H_ * 2);
  u16*  hp0    = (u16*)alloc((size_t)2 * B_ * H_ * 2);
  u16*  hp1    = (u16*)alloc((size_t)2 * B_ * H_ * 2);
  float* raw    = (float*)alloc((size_t)B_ * NDP * 4);
  u16*  Gbuf   = (u16*)alloc((size_t)256 * 512 * 32 * 2);
  u16*  Ldbuf  = (u16*)alloc((size_t)256 * 512 * 32 * 2);
  float* idio   = (float*)alloc((size_t)256 * 512 * 4);
  unsigned* bars0 = (unsigned*)alloc(16 * 32 * 4);
  unsigned* bars1 = (unsigned*)alloc(16 * 32 * 4);

  hipMemsetAsync(hp0, 0, (size_t)2 * B_ * H_ * 2, stream);
  hipMemsetAsync(hp1, 0, (size_t)2 * B_ * H_ * 2, stream);
  hipMemsetAsync(bars0, 0, 16 * 32 * 4, stream);
  hipMemsetAsync(bars1, 0, 16 * 32 * 4, stream);

  dim3 blk(256);
  prep_weights_kernel<<<512, blk, 0, stream>>>(w_ih0, w_hh0, b_ih0, b_hh0,
                                               w_ih1, w_hh1, b_ih1, b_hh1,
                                               fc_w, fc_b,
                                               wih0b, whh0b, w1b, fcwb,
                                               bias0p, bias1p, fcbp);
  prep_x_kernel<<<1024, blk, 0, stream>>>(x, xb);

  // xg0 = xb @ wih0b^T + (b_ih0 + b_hh0)   [16384 x 2048 x 512]
  gemm_bt<1><<<dim3(G_ / 128, (T_ * B_) / 128), blk, 0, stream>>>(
      xb, wih0b, bias0p, xg0, T_ * B_, G_, 512);

  lstm0_kernel<<<512, blk, 0, stream>>>(xg0, whh0b, hp0, h0all, bars0);
  lstm1_kernel<<<512, blk, 0, stream>>>(h0all, w1b, bias1p, hp1, bars1);

  // raw = h1_final @ fcwb^T + fc_b  [256 x 16640 x 512]; final h1 is in hp1 buffer 0
  gemm_bt<0><<<dim3(NDP / 128, B_ / 128), blk, 0, stream>>>(
      hp1, fcwb, fcbp, raw, B_, NDP, 512);

  prep_sigma_kernel<<<1024, blk, 0, stream>>>(raw, Gbuf, Ldbuf, idio);
  sigma_kernel<<<dim3(4, 4, 256), blk, 0, stream>>>(Gbuf, Ldbuf, idio, out);
}

// Round 2
// 1215.715 us; speedup vs baseline: 6.7174x; 6.7174x over previous
//
#include <hip/hip_runtime.h>

typedef __bf16 bf16_t;
typedef bf16_t bf16x8 __attribute__((ext_vector_type(8)));
typedef float  floatx4 __attribute__((ext_vector_type(4)));
typedef unsigned short u16;
typedef unsigned long long u64;

#define DEV __device__ __forceinline__

static constexpr int B_  = 256;
static constexpr int T_  = 64;
static constexpr int H_  = 512;
static constexpr int G_  = 2048;   // 4*H
static constexpr int INS = 500;
static constexpr int NDP = 16640;  // padded OUT_DIM
static constexpr int NDR = 16532;  // real OUT_DIM

DEV u16 f2bf(float f) {
  unsigned u = __builtin_bit_cast(unsigned, f);
  u += 0x7FFFu + ((u >> 16) & 1u);
  return (u16)(u >> 16);
}
DEV float bf2f(u16 h) {
  unsigned u = ((unsigned)h) << 16;
  return __builtin_bit_cast(float, u);
}
DEV float sigm(float x)  { return 1.f / (1.f + __expf(-x)); }
DEV float tanh_(float x) { return 1.f - 2.f / (__expf(2.f * x) + 1.f); }

// ---------------------------------------------------------------- prep kernels
__global__ void prep_weights_kernel(
    const float* __restrict__ w_ih0, const float* __restrict__ w_hh0,
    const float* __restrict__ b_ih0, const float* __restrict__ b_hh0,
    const float* __restrict__ w_ih1, const float* __restrict__ w_hh1,
    const float* __restrict__ b_ih1, const float* __restrict__ b_hh1,
    const float* __restrict__ fc_w,  const float* __restrict__ fc_b,
    u16* __restrict__ wih0b, u16* __restrict__ whh0b,
    u16* __restrict__ w1b,   u16* __restrict__ fcwb,
    float* __restrict__ bias0p, float* __restrict__ bias1p,
    float* __restrict__ fcbp)
{
  const int gsz = gridDim.x * blockDim.x;
  const int g0  = blockIdx.x * blockDim.x + threadIdx.x;
  // permuted gate order: p = (j>>4)*64 + (j&15)*4 + g  (j = hidden, g = i/f/g/o)
  for (int i = g0; i < 2048 * 512; i += gsz) {
    int pp = i >> 9, k = i & 511;
    int s = pp >> 6, rr = pp & 63, jj = rr >> 2, g = rr & 3;
    int srow = g * 512 + s * 16 + jj;
    wih0b[i] = f2bf(k < INS ? w_ih0[(size_t)srow * INS + k] : 0.f);
    whh0b[i] = f2bf(w_hh0[(size_t)srow * 512 + k]);
  }
  for (int i = g0; i < 2048 * 1024; i += gsz) {
    int pp = i >> 10, k = i & 1023;
    int s = pp >> 6, rr = pp & 63, jj = rr >> 2, g = rr & 3;
    int srow = g * 512 + s * 16 + jj;
    float v = (k < 512) ? w_ih1[(size_t)srow * 512 + k]
                        : w_hh1[(size_t)srow * 512 + (k - 512)];
    w1b[i] = f2bf(v);
  }
  for (int i = g0; i < NDP * 512; i += gsz) {
    int n = i >> 9, k = i & 511;
    fcwb[i] = f2bf(n < NDR ? fc_w[(size_t)n * 512 + k] : 0.f);
  }
  for (int i = g0; i < 2048; i += gsz) {
    int s = i >> 6, rr = i & 63, jj = rr >> 2, g = rr & 3;
    int srow = g * 512 + s * 16 + jj;
    bias0p[i] = b_ih0[srow] + b_hh0[srow];
    bias1p[i] = b_ih1[srow] + b_hh1[srow];
  }
  for (int i = g0; i < NDP; i += gsz) fcbp[i] = (i < NDR) ? fc_b[i] : 0.f;
}

__global__ void prep_x_kernel(const float* __restrict__ x, u16* __restrict__ xb) {
  const int gsz = gridDim.x * blockDim.x;
  for (int i = blockIdx.x * blockDim.x + threadIdx.x; i < T_ * B_ * 512; i += gsz) {
    int k = i & 511;
    int b = (i >> 9) & 255;
    int t = i >> 17;
    float v = (k < INS) ? x[((size_t)b * T_ + t) * INS + k] : 0.f;
    xb[i] = f2bf(v);
  }
}

__global__ void prep_sigma_kernel(const float* __restrict__ raw,
                                  u16* __restrict__ Gb, u16* __restrict__ Ldb,
                                  float* __restrict__ idio)
{
  const int gsz = gridDim.x * blockDim.x;
  const int g0  = blockIdx.x * blockDim.x + threadIdx.x;
  for (int i = g0; i < 256 * 512 * 32; i += gsz) {
    int b = i >> 14, rr = i & 16383, n = rr >> 5, f = rr & 31;
    const float* rb = raw + (size_t)b * NDP;
    float ld = (n < 500) ? rb[n * 32 + f] : 0.f;
    float fv = __expf(rb[16000 + f]);
    Ldb[i] = f2bf(ld);
    Gb[i]  = f2bf(ld * fv);
  }
  for (int i = g0; i < 256 * 512; i += gsz) {
    int b = i >> 9, a = i & 511;
    if (a < 500) idio[(size_t)b * 500 + a] = __expf(raw[(size_t)b * NDP + 16032 + a]);
  }
}

// ---------------------------------------------------------------- GEMM: C[M][N] = A[M][K] @ Bw[N][K]^T + bias
template <int OUT_BF16>
__global__ __launch_bounds__(256) void gemm_bt(
    const u16* __restrict__ A, const u16* __restrict__ Bw,
    const float* __restrict__ bias, void* __restrict__ C,
    int M, int N, int K)
{
  __shared__ alignas(16) u16 As[128 * 32];
  __shared__ alignas(16) u16 Bs[128 * 32];
  const int tid = threadIdx.x;
  const int wave = tid >> 6, lane = tid & 63;
  const int m0 = blockIdx.y * 128, n0 = blockIdx.x * 128;
  const int wr = wave >> 1, wc = wave & 1;

  floatx4 zero = {0.f, 0.f, 0.f, 0.f};
  floatx4 acc[4][4];
#pragma unroll
  for (int i = 0; i < 4; i++)
#pragma unroll
    for (int j = 0; j < 4; j++) acc[i][j] = zero;

  uint4 ra[2], rb[2];
#pragma unroll
  for (int i = 0; i < 2; i++) {
    int idx = tid + (i << 8);
    int row = idx >> 2, ks = idx & 3;
    ra[i] = *(const uint4*)(A  + (size_t)(m0 + row) * K + ks * 8);
    rb[i] = *(const uint4*)(Bw + (size_t)(n0 + row) * K + ks * 8);
  }

  for (int kc = 0; kc < K; kc += 32) {
    __syncthreads();
#pragma unroll
    for (int i = 0; i < 2; i++) {
      int idx = tid + (i << 8);
      int row = idx >> 2, ks = idx & 3;
      int off = row * 32 + ((ks ^ (row & 3)) << 3);   // XOR swizzle vs bank conflicts
      *(uint4*)(As + off) = ra[i];
      *(uint4*)(Bs + off) = rb[i];
    }
    __syncthreads();
    if (kc + 32 < K) {
#pragma unroll
      for (int i = 0; i < 2; i++) {
        int idx = tid + (i << 8);
        int row = idx >> 2, ks = idx & 3;
        ra[i] = *(const uint4*)(A  + (size_t)(m0 + row) * K + kc + 32 + ks * 8);
        rb[i] = *(const uint4*)(Bw + (size_t)(n0 + row) * K + kc + 32 + ks * 8);
      }
    }
    const int kg = lane >> 4;
    bf16x8 af[4], bfr[4];
#pragma unroll
    for (int i = 0; i < 4; i++) {
      int rowa = wr * 64 + i * 16 + (lane & 15);
      af[i] = *(const bf16x8*)(As + rowa * 32 + ((kg ^ (rowa & 3)) << 3));
      int rowb = wc * 64 + i * 16 + (lane & 15);
      bfr[i] = *(const bf16x8*)(Bs + rowb * 32 + ((kg ^ (rowb & 3)) << 3));
    }
#pragma unroll
    for (int i = 0; i < 4; i++)
#pragma unroll
      for (int j = 0; j < 4; j++)
        acc[i][j] = __builtin_amdgcn_mfma_f32_16x16x32_bf16(af[i], bfr[j], acc[i][j], 0, 0, 0);
  }

  const int r0 = (lane >> 4) * 4, cl = lane & 15;
#pragma unroll
  for (int j = 0; j < 4; j++) {
    int col = n0 + wc * 64 + j * 16 + cl;
    float bv = bias[col];
#pragma unroll
    for (int i = 0; i < 4; i++) {
      int row = m0 + wr * 64 + i * 16 + r0;
#pragma unroll
      for (int r = 0; r < 4; r++) {
        float v = acc[i][j][r] + bv;
        if (OUT_BF16) ((u16*)C)[(size_t)(row + r) * N + col] = f2bf(v);
        else          ((float*)C)[(size_t)(row + r) * N + col] = v;
      }
    }
  }
}

// ---------------------------------------------------------------- LSTM layer 0
// 512 blocks: bm=blockIdx>>5 (16 batch groups of 16), bn=blockIdx&31 (32 hidden slices).
// W_hh fragments in registers. Cross-block h + barrier use agent-scope RELAXED
// atomics ONLY (sc0/sc1 -> coherence point) — no __threadfence, no L2 flush.
// Ordering: compiler drains vmcnt(0) before s_barrier, so all waves' h-stores
// are ack'd at the coherence point before lane 0 increments the counter.
__global__ __launch_bounds__(256, 2) void lstm0_kernel(
    const u16* __restrict__ xg,     // [64][256][2048] bf16, permuted gate order
    const u16* __restrict__ whh,    // [2048][512] bf16, permuted rows
    u16* __restrict__ hping,        // [2][256][512]
    u16* __restrict__ h0all,        // [64][256][512]
    unsigned* __restrict__ bars)    // [16]
{
  const int tid = threadIdx.x;
  const int wave = tid >> 6, lane = tid & 63;
  const int bm = blockIdx.x >> 5;
  const int bn = blockIdx.x & 31;
  const int bbase = bm << 4;
  const int pbase = bn << 6;

  __shared__ alignas(16) u16 h_lds[16 * 512];
  __shared__ alignas(16) float gates_lds[16 * 68];   // pad 64->68: no 4-way conflict

  bf16x8 wfrag[16];
  {
    const u16* wp = whh + (size_t)(pbase + wave * 16 + (lane & 15)) * 512 + (lane >> 4) * 8;
#pragma unroll
    for (int kc = 0; kc < 16; kc++) wfrag[kc] = *(const bf16x8*)(wp + kc * 32);
  }

  const int qb = tid >> 4, qj = tid & 15;
  float c = 0.f;
  unsigned target = 0;
  unsigned* mybar = bars + bm * 32;
  const floatx4 zero = {0.f, 0.f, 0.f, 0.f};

#pragma unroll 1
  for (int t = 0; t < 64; t++) {
    const int cur = t & 1, nxt = cur ^ 1;
    {
      const u64* hsrc = (const u64*)(hping + (size_t)cur * (B_ * H_) + (size_t)bbase * H_);
#pragma unroll
      for (int i = 0; i < 4; i++) {
        int idx = tid + (i << 8);
        int b = idx >> 6, kg = idx & 63;
        u64 lo = __hip_atomic_load(hsrc + idx * 2,     __ATOMIC_RELAXED, __HIP_MEMORY_SCOPE_AGENT);
        u64 hi = __hip_atomic_load(hsrc + idx * 2 + 1, __ATOMIC_RELAXED, __HIP_MEMORY_SCOPE_AGENT);
        int off = b * 512 + ((kg ^ (b & 7)) << 3);
        *(u64*)(h_lds + off)     = lo;
        *(u64*)(h_lds + off + 4) = hi;
      }
    }
    __syncthreads();
    floatx4 acc = zero;
    {
      const int b = lane & 15, qd = lane >> 4;
#pragma unroll
      for (int kc = 0; kc < 16; kc++) {
        int kgrp = kc * 4 + qd;
        bf16x8 a = *(const bf16x8*)(h_lds + b * 512 + ((kgrp ^ (b & 7)) << 3));
        acc = __builtin_amdgcn_mfma_f32_16x16x32_bf16(a, wfrag[kc], acc, 0, 0, 0);
      }
    }
    {
      int r0 = (lane >> 4) * 4, cc = wave * 16 + (lane & 15);
#pragma unroll
      for (int r = 0; r < 4; r++) gates_lds[(r0 + r) * 68 + cc] = acc[r];
    }
    __syncthreads();
    {
      const float4 gm = *(const float4*)(gates_lds + qb * 68 + qj * 4);
      const u16* xq = xg + ((size_t)t * B_ + bbase + qb) * G_ + pbase + qj * 4;
      ushort4 xr = *(const ushort4*)xq;
      float gi = gm.x + bf2f(xr.x);
      float gf = gm.y + bf2f(xr.y);
      float gg = gm.z + bf2f(xr.z);
      float go = gm.w + bf2f(xr.w);
      c = sigm(gf) * c + sigm(gi) * tanh_(gg);
      float h = sigm(go) * tanh_(c);
      u16 hb = f2bf(h);
      size_t hoff = (size_t)(bbase + qb) * H_ + (bn << 4) + qj;
      __hip_atomic_store(hping + (size_t)nxt * (B_ * H_) + hoff, hb,
                         __ATOMIC_RELAXED, __HIP_MEMORY_SCOPE_AGENT);
      h0all[(size_t)t * (B_ * H_) + hoff] = hb;   // consumed only by next kernel
    }
    target += 32;
    if (t < 63) {
      __syncthreads();   // drains vmcnt(0) for ALL waves' h stores
      if (tid == 0) {
        __hip_atomic_fetch_add(mybar, 1u, __ATOMIC_RELAXED, __HIP_MEMORY_SCOPE_AGENT);
        while (__hip_atomic_load(mybar, __ATOMIC_RELAXED, __HIP_MEMORY_SCOPE_AGENT) < target)
          __builtin_amdgcn_s_sleep(2);
      }
      __syncthreads();
    }
  }
}

// ---------------------------------------------------------------- LSTM layer 1 (input proj folded in: K=1024 = [h0_t | h1])
__global__ __launch_bounds__(256, 2) void lstm1_kernel(
    const u16* __restrict__ h0all,  // [64][256][512]
    const u16* __restrict__ w1,     // [2048][1024] bf16 permuted rows, cols = [w_ih1 | w_hh1]
    const float* __restrict__ bias1p,
    u16* __restrict__ hping,        // [2][256][512]; final h1 ends in buffer 0
    unsigned* __restrict__ bars)
{
  const int tid = threadIdx.x;
  const int wave = tid >> 6, lane = tid & 63;
  const int bm = blockIdx.x >> 5;
  const int bn = blockIdx.x & 31;
  const int bbase = bm << 4;
  const int pbase = bn << 6;

  __shared__ alignas(16) u16 h_lds[2 * 16 * 512];
  __shared__ alignas(16) float gates_lds[16 * 68];

  bf16x8 wfrag[32];
  {
    const u16* wp = w1 + (size_t)(pbase + wave * 16 + (lane & 15)) * 1024 + (lane >> 4) * 8;
#pragma unroll
    for (int kc = 0; kc < 32; kc++) wfrag[kc] = *(const bf16x8*)(wp + kc * 32);
  }

  const int qb = tid >> 4, qj = tid & 15;
  const float4 bq = *(const float4*)(bias1p + pbase + qj * 4);
  float c = 0.f;
  unsigned target = 0;
  unsigned* mybar = bars + bm * 32;
  const floatx4 zero = {0.f, 0.f, 0.f, 0.f};

#pragma unroll 1
  for (int t = 0; t < 64; t++) {
    const int cur = t & 1, nxt = cur ^ 1;
    {
      const u16* s0 = h0all + (size_t)t * (B_ * H_) + (size_t)bbase * H_;
      const u64* s1 = (const u64*)(hping + (size_t)cur * (B_ * H_) + (size_t)bbase * H_);
#pragma unroll
      for (int i = 0; i < 4; i++) {
        int idx = tid + (i << 8);
        int b = idx >> 6, kg = idx & 63;
        int dst = b * 512 + ((kg ^ (b & 7)) << 3);
        *(uint4*)(h_lds + dst) = *(const uint4*)(s0 + idx * 8);   // plain: kernel-boundary coherent
        u64 lo = __hip_atomic_load(s1 + idx * 2,     __ATOMIC_RELAXED, __HIP_MEMORY_SCOPE_AGENT);
        u64 hi = __hip_atomic_load(s1 + idx * 2 + 1, __ATOMIC_RELAXED, __HIP_MEMORY_SCOPE_AGENT);
        *(u64*)(h_lds + 8192 + dst)     = lo;
        *(u64*)(h_lds + 8192 + dst + 4) = hi;
      }
    }
    __syncthreads();
    floatx4 acc = zero;
    {
      const int b = lane & 15, qd = lane >> 4;
#pragma unroll
      for (int kc = 0; kc < 32; kc++) {
        int reg = (kc >> 4) * 8192;
        int kgrp = (kc & 15) * 4 + qd;
        bf16x8 a = *(const bf16x8*)(h_lds + reg + b * 512 + ((kgrp ^ (b & 7)) << 3));
        acc = __builtin_amdgcn_mfma_f32_16x16x32_bf16(a, wfrag[kc], acc, 0, 0, 0);
      }
    }
    {
      int r0 = (lane >> 4) * 4, cc = wave * 16 + (lane & 15);
#pragma unroll
      for (int r = 0; r < 4; r++) gates_lds[(r0 + r) * 68 + cc] = acc[r];
    }
    __syncthreads();
    {
      const float4 gm = *(const float4*)(gates_lds + qb * 68 + qj * 4);
      float gi = gm.x + bq.x;
      float gf = gm.y + bq.y;
      float gg = gm.z + bq.z;
      float go = gm.w + bq.w;
      c = sigm(gf) * c + sigm(gi) * tanh_(gg);
      float h = sigm(go) * tanh_(c);
      size_t hoff = (size_t)(bbase + qb) * H_ + (bn << 4) + qj;
      __hip_atomic_store(hping + (size_t)nxt * (B_ * H_) + hoff, f2bf(h),
                         __ATOMIC_RELAXED, __HIP_MEMORY_SCOPE_AGENT);
    }
    target += 32;
    if (t < 63) {
      __syncthreads();
      if (tid == 0) {
        __hip_atomic_fetch_add(mybar, 1u, __ATOMIC_RELAXED, __HIP_MEMORY_SCOPE_AGENT);
        while (__hip_atomic_load(mybar, __ATOMIC_RELAXED, __HIP_MEMORY_SCOPE_AGENT) < target)
          __builtin_amdgcn_s_sleep(2);
      }
      __syncthreads();
    }
  }
}

// ---------------------------------------------------------------- Sigma: out[b] = G_b @ Ld_b^T + diag(idio)
__global__ __launch_bounds__(256) void sigma_kernel(
    const u16* __restrict__ Gb, const u16* __restrict__ Ldb,
    const float* __restrict__ idio, float* __restrict__ out)
{
  const int bz = blockIdx.z;
  const int n0 = blockIdx.y * 128;
  const int m0 = blockIdx.x * 128;
  __shared__ alignas(16) u16 As[128 * 32];
  __shared__ alignas(16) u16 Bs[128 * 32];
  const int tid = threadIdx.x, wave = tid >> 6, lane = tid & 63;
  const int wr = wave >> 1, wc = wave & 1;

  const u16* ga = Gb  + (size_t)bz * (512 * 32) + n0 * 32;
  const u16* gb = Ldb + (size_t)bz * (512 * 32) + m0 * 32;
#pragma unroll
  for (int i = 0; i < 2; i++) {
    int idx = tid + (i << 8);
    int row = idx >> 2, ks = idx & 3;
    int off = row * 32 + ((ks ^ (row & 3)) << 3);
    *(uint4*)(As + off) = *(const uint4*)(ga + idx * 8);
    *(uint4*)(Bs + off) = *(const uint4*)(gb + idx * 8);
  }
  __syncthreads();

  const int kg = lane >> 4;
  bf16x8 af[4], bfr[4];
#pragma unroll
  for (int i = 0; i < 4; i++) {
    int rowa = wr * 64 + i * 16 + (lane & 15);
    af[i] = *(const bf16x8*)(As + rowa * 32 + ((kg ^ (rowa & 3)) << 3));
    int rowb = wc * 64 + i * 16 + (lane & 15);
    bfr[i] = *(const bf16x8*)(Bs + rowb * 32 + ((kg ^ (rowb & 3)) << 3));
  }
  floatx4 zero = {0.f, 0.f, 0.f, 0.f};
  floatx4 acc[4][4];
#pragma unroll
  for (int i = 0; i < 4; i++)
#pragma unroll
    for (int j = 0; j < 4; j++)
      acc[i][j] = __builtin_amdgcn_mfma_f32_16x16x32_bf16(af[i], bfr[j], zero, 0, 0, 0);

  const int r0 = (lane >> 4) * 4, cl = lane & 15;
  float* ob = out + (size_t)bz * 250000;
#pragma unroll
  for (int j = 0; j < 4; j++) {
    int col = m0 + wc * 64 + j * 16 + cl;
#pragma unroll
    for (int i = 0; i < 4; i++) {
      int row = n0 + wr * 64 + i * 16 + r0;
#pragma unroll
      for (int r = 0; r < 4; r++) {
        int rr = row + r;
        if (rr < 500 && col < 500) {
          float v = acc[i][j][r];
          if (rr == col) v += idio[(size_t)bz * 500 + rr];
          ob[(size_t)rr * 500 + col] = v;
        }
      }
    }
  }
}

// ---------------------------------------------------------------- launcher
extern "C" void kernel_launch(void* const* d_in, const int* in_sizes, int n_in,
                              void* d_out, int out_size, void* d_ws, size_t ws_size,
                              hipStream_t stream)
{
  const float* x     = (const float*)d_in[0];
  const float* w_ih0 = (const float*)d_in[1];
  const float* w_hh0 = (const float*)d_in[2];
  const float* b_ih0 = (const float*)d_in[3];
  const float* b_hh0 = (const float*)d_in[4];
  const float* w_ih1 = (const float*)d_in[5];
  const float* w_hh1 = (const float*)d_in[6];
  const float* b_ih1 = (const float*)d_in[7];
  const float* b_hh1 = (const float*)d_in[8];
  const float* fc_w  = (const float*)d_in[9];
  const float* fc_b  = (const float*)d_in[10];
  float* out = (float*)d_out;

  char* p = (char*)d_ws;
  auto alloc = [&](size_t n) { char* r = p; p += (n + 255) & ~(size_t)255; return r; };

  u16*  xb     = (u16*)alloc((size_t)T_ * B_ * 512 * 2);
  u16*  wih0b  = (u16*)alloc((size_t)2048 * 512 * 2);
  u16*  whh0b  = (u16*)alloc((size_t)2048 * 512 * 2);
  u16*  w1b    = (u16*)alloc((size_t)2048 * 1024 * 2);
  u16*  fcwb   = (u16*)alloc((size_t)NDP * 512 * 2);
  float* bias0p = (float*)alloc(2048 * 4);
  float* bias1p = (float*)alloc(2048 * 4);
  float* fcbp   = (float*)alloc((size_t)NDP * 4);
  u16*  xg0    = (u16*)alloc((size_t)T_ * B_ * G_ * 2);
  u16*  h0all  = (u16*)alloc((size_t)T_ * B_ * H_ * 2);
  u16*  hp0    = (u16*)alloc((size_t)2 * B_ * H_ * 2);
  u16*  hp1    = (u16*)alloc((size_t)2 * B_ * H_ * 2);
  float* raw    = (float*)alloc((size_t)B_ * NDP * 4);
  u16*  Gbuf   = (u16*)alloc((size_t)256 * 512 * 32 * 2);
  u16*  Ldbuf  = (u16*)alloc((size_t)256 * 512 * 32 * 2);
  float* idio   = (float*)alloc((size_t)256 * 512 * 4);
  unsigned* bars0 = (unsigned*)alloc(16 * 32 * 4);
  unsigned* bars1 = (unsigned*)alloc(16 * 32 * 4);

  hipMemsetAsync(hp0, 0, (size_t)2 * B_ * H_ * 2, stream);
  hipMemsetAsync(hp1, 0, (size_t)2 * B_ * H_ * 2, stream);
  hipMemsetAsync(bars0, 0, 16 * 32 * 4, stream);
  hipMemsetAsync(bars1, 0, 16 * 32 * 4, stream);

  dim3 blk(256);
  prep_weights_kernel<<<512, blk, 0, stream>>>(w_ih0, w_hh0, b_ih0, b_hh0,
                                               w_ih1, w_hh1, b_ih1, b_hh1,
                                               fc_w, fc_b,
                                               wih0b, whh0b, w1b, fcwb,
                                               bias0p, bias1p, fcbp);
  prep_x_kernel<<<1024, blk, 0, stream>>>(x, xb);

  // xg0 = xb @ wih0b^T + (b_ih0 + b_hh0)   [16384 x 2048 x 512]
  gemm_bt<1><<<dim3(G_ / 128, (T_ * B_) / 128), blk, 0, stream>>>(
      xb, wih0b, bias0p, xg0, T_ * B_, G_, 512);

  lstm0_kernel<<<512, blk, 0, stream>>>(xg0, whh0b, hp0, h0all, bars0);
  lstm1_kernel<<<512, blk, 0, stream>>>(h0all, w1b, bias1p, hp1, bars1);

  // raw = h1_final @ fcwb^T + fc_b  [256 x 16640 x 512]; final h1 is in hp1 buffer 0
  gemm_bt<0><<<dim3(NDP / 128, B_ / 128), blk, 0, stream>>>(
      hp1, fcwb, fcbp, raw, B_, NDP, 512);

  prep_sigma_kernel<<<1024, blk, 0, stream>>>(raw, Gbuf, Ldbuf, idio);
  sigma_kernel<<<dim3(4, 4, 256), blk, 0, stream>>>(Gbuf, Ldbuf, idio, out);
}